// Round 4
// baseline (605.344 us; speedup 1.0000x reference)
//
#include <hip/hip_runtime.h>

#define RR 32
#define R3 32768
#define BATCH 8
#define CH 64
#define NPTS 100000
#define NPOINTS (BATCH * NPTS)   // 800000
#define NVOX (BATCH * R3)        // 262144
#define SCAN_BLOCKS (NVOX / 256) // 1024

typedef unsigned int uint32;
typedef unsigned int uintx4 __attribute__((ext_vector_type(4)));
typedef unsigned int uintx2 __attribute__((ext_vector_type(2)));
typedef float floatx2 __attribute__((ext_vector_type(2)));

__device__ __forceinline__ uint32 f2bf(float f) {
    uint32 u = __float_as_uint(f);
    return (u + 0x7fffu + ((u >> 16) & 1u)) >> 16;   // RNE to bf16
}
__device__ __forceinline__ float bf2f(uint32 h) {
    return __uint_as_float(h << 16);
}

// ---------------------------------------------------------------------------
// Phase 1: voxel id per point + histogram + coords output. 2 points/thread.
// ---------------------------------------------------------------------------
__global__ __launch_bounds__(256) void phase1_count(
    const float* __restrict__ coords,  // [B, 3, N]
    uint32* __restrict__ vox,          // [NPOINTS]
    uint32* __restrict__ cnt,          // [NVOX] (pre-zeroed)
    float* __restrict__ out2)          // [B, 3, N] voxel coords as float
{
    int pid = blockIdx.x * blockDim.x + threadIdx.x;   // pair id
    if (pid >= NPOINTS / 2) return;
    int p0 = pid * 2;
    int b = p0 / NPTS;
    int n = p0 - b * NPTS;             // even; pair always within one batch

    const float* cb = coords + (size_t)b * 3 * NPTS + n;
    floatx2 cx = *(const floatx2*)(cb);
    floatx2 cy = *(const floatx2*)(cb + NPTS);
    floatx2 cz = *(const floatx2*)(cb + 2 * NPTS);

    int x0 = (int)rintf(fminf(fmaxf(cx.x * 32.0f, 0.0f), 31.0f));
    int y0 = (int)rintf(fminf(fmaxf(cy.x * 32.0f, 0.0f), 31.0f));
    int z0 = (int)rintf(fminf(fmaxf(cz.x * 32.0f, 0.0f), 31.0f));
    int x1 = (int)rintf(fminf(fmaxf(cx.y * 32.0f, 0.0f), 31.0f));
    int y1 = (int)rintf(fminf(fmaxf(cy.y * 32.0f, 0.0f), 31.0f));
    int z1 = (int)rintf(fminf(fmaxf(cz.y * 32.0f, 0.0f), 31.0f));

    uint32 g0 = (uint32)(b * R3 + x0 * (RR * RR) + y0 * RR + z0);
    uint32 g1 = (uint32)(b * R3 + x1 * (RR * RR) + y1 * RR + z1);

    float* o2 = out2 + (size_t)b * 3 * NPTS + n;
    *(floatx2*)(o2)            = floatx2{(float)x0, (float)x1};
    *(floatx2*)(o2 + NPTS)     = floatx2{(float)y0, (float)y1};
    *(floatx2*)(o2 + 2 * NPTS) = floatx2{(float)z0, (float)z1};

    *(uintx2*)(vox + p0) = uintx2{g0, g1};
    atomicAdd(&cnt[g0], 1u);
    atomicAdd(&cnt[g1], 1u);
}

// ---------------------------------------------------------------------------
// Phase 2: exclusive scan over cnt[NVOX] -> starts[], cursor[].
// ---------------------------------------------------------------------------
__global__ __launch_bounds__(256) void scan_block_sums(
    const uint32* __restrict__ cnt, uint32* __restrict__ bsum)
{
    __shared__ uint32 s[256];
    int t = threadIdx.x;
    s[t] = cnt[blockIdx.x * 256 + t];
    __syncthreads();
    for (int off = 128; off > 0; off >>= 1) {
        if (t < off) s[t] += s[t + off];
        __syncthreads();
    }
    if (t == 0) bsum[blockIdx.x] = s[0];
}

__global__ __launch_bounds__(256) void scan_bsum(uint32* __restrict__ bsum)
{
    __shared__ uint32 s[256];
    int t = threadIdx.x;
    uint32 v0 = bsum[4 * t], v1 = bsum[4 * t + 1], v2 = bsum[4 * t + 2], v3 = bsum[4 * t + 3];
    uint32 tot = v0 + v1 + v2 + v3;
    s[t] = tot;
    __syncthreads();
    for (int off = 1; off < 256; off <<= 1) {
        uint32 x = (t >= off) ? s[t - off] : 0u;
        __syncthreads();
        s[t] += x;
        __syncthreads();
    }
    uint32 excl = s[t] - tot;
    bsum[4 * t]     = excl;
    bsum[4 * t + 1] = excl + v0;
    bsum[4 * t + 2] = excl + v0 + v1;
    bsum[4 * t + 3] = excl + v0 + v1 + v2;
}

__global__ __launch_bounds__(256) void scan_final(
    const uint32* __restrict__ cnt, const uint32* __restrict__ bsum,
    uint32* __restrict__ starts, uint32* __restrict__ cursor)
{
    __shared__ uint32 s[256];
    int t = threadIdx.x;
    int gid = blockIdx.x * 256 + t;
    uint32 v = cnt[gid];
    s[t] = v;
    __syncthreads();
    for (int off = 1; off < 256; off <<= 1) {
        uint32 x = (t >= off) ? s[t - off] : 0u;
        __syncthreads();
        s[t] += x;
        __syncthreads();
    }
    uint32 st = bsum[blockIdx.x] + s[t] - v;
    starts[gid] = st;
    cursor[gid] = st;
}

// ---------------------------------------------------------------------------
// Phase 3: scatter features (bf16x2 packed, 128 B/point). 2 points/thread,
// floatx2 reads (halved load instrs), nontemporal loads+stores.
// ---------------------------------------------------------------------------
__global__ __launch_bounds__(256) void phase3_scatter(
    const float* __restrict__ feat,    // [B, C, N]
    const uint32* __restrict__ vox,
    uint32* __restrict__ cursor,
    uintx4* __restrict__ sorted)       // [NPOINTS][8] uintx4
{
    int pid = blockIdx.x * blockDim.x + threadIdx.x;
    if (pid >= NPOINTS / 2) return;
    int p0 = pid * 2;
    int b = p0 / NPTS;
    int n = p0 - b * NPTS;

    uintx2 gg = *(const uintx2*)(vox + p0);
    uint32 pos0 = atomicAdd(&cursor[gg.x], 1u);
    uint32 pos1 = atomicAdd(&cursor[gg.y], 1u);

    const float* frow = feat + (size_t)b * CH * NPTS + n;
    uintx4* d0 = sorted + (size_t)pos0 * 8;
    uintx4* d1 = sorted + (size_t)pos1 * 8;

#pragma unroll
    for (int j = 0; j < 8; ++j) {
        floatx2 f[8];
#pragma unroll
        for (int i = 0; i < 8; ++i)
            f[i] = __builtin_nontemporal_load(
                (const floatx2*)(frow + (size_t)(8 * j + i) * NPTS));
        uintx4 w0, w1;
        w0.x = f2bf(f[0].x) | (f2bf(f[1].x) << 16);
        w0.y = f2bf(f[2].x) | (f2bf(f[3].x) << 16);
        w0.z = f2bf(f[4].x) | (f2bf(f[5].x) << 16);
        w0.w = f2bf(f[6].x) | (f2bf(f[7].x) << 16);
        w1.x = f2bf(f[0].y) | (f2bf(f[1].y) << 16);
        w1.y = f2bf(f[2].y) | (f2bf(f[3].y) << 16);
        w1.z = f2bf(f[4].y) | (f2bf(f[5].y) << 16);
        w1.w = f2bf(f[6].y) | (f2bf(f[7].y) << 16);
        __builtin_nontemporal_store(w0, d0 + j);
        __builtin_nontemporal_store(w1, d1 + j);
    }
}

// ---------------------------------------------------------------------------
// Phase 4: 8 lanes per voxel, uintx4 (dwordx4) reads -> full-wave utilization,
// serial depth ~6. Padded-LDS transpose + fused divide, coalesced writes.
// ---------------------------------------------------------------------------
__global__ __launch_bounds__(256) void phase4_reduce(
    const uint32* __restrict__ sorted,   // [NPOINTS][32] uint (bf16x2)
    const uint32* __restrict__ starts,
    float* __restrict__ out1)            // [B, C, R3]
{
    __shared__ float tile[64][65];

    int gbase = blockIdx.x * 64;
    int tid = threadIdx.x;
    int w = tid >> 6, lane = tid & 63;
    int gq = lane >> 3, l8 = lane & 7;

#pragma unroll
    for (int iter = 0; iter < 2; ++iter) {
        int vloc = w * 16 + iter * 8 + gq;
        int g = gbase + vloc;
        uint32 s = starts[g];
        uint32 e = (g == NVOX - 1) ? (uint32)NPOINTS : starts[g + 1];
        float a0 = 0.f, a1 = 0.f, a2 = 0.f, a3 = 0.f;
        float a4 = 0.f, a5 = 0.f, a6 = 0.f, a7 = 0.f;
        for (uint32 p = s; p < e; ++p) {
            uintx4 wv = __builtin_nontemporal_load(
                (const uintx4*)(sorted + (size_t)p * 32) + l8);
            a0 += bf2f(wv.x & 0xffffu); a1 += bf2f(wv.x >> 16);
            a2 += bf2f(wv.y & 0xffffu); a3 += bf2f(wv.y >> 16);
            a4 += bf2f(wv.z & 0xffffu); a5 += bf2f(wv.z >> 16);
            a6 += bf2f(wv.w & 0xffffu); a7 += bf2f(wv.w >> 16);
        }
        uint32 c = e - s;
        float rcp = 1.0f / (float)(c > 1u ? c : 1u);
        float* trow = &tile[vloc][l8 * 8];
        trow[0] = a0 * rcp; trow[1] = a1 * rcp;
        trow[2] = a2 * rcp; trow[3] = a3 * rcp;
        trow[4] = a4 * rcp; trow[5] = a5 * rcp;
        trow[6] = a6 * rcp; trow[7] = a7 * rcp;
    }
    __syncthreads();

    int b = gbase / R3;
    int v0 = gbase & (R3 - 1);
    int vv = tid & 63;
    int c0 = tid >> 6;
    float* obase = out1 + (size_t)b * CH * R3 + v0 + vv;
#pragma unroll
    for (int jj = 0; jj < 16; ++jj) {
        int c = jj * 4 + c0;
        obase[(size_t)c * R3] = tile[vv][c];
    }
}

// ---------------------------------------------------------------------------
// Fallback (small ws): direct atomic accumulate into d_out.
// ---------------------------------------------------------------------------
__global__ __launch_bounds__(256) void accum_direct(
    const float* __restrict__ feat, const float* __restrict__ coords,
    float* __restrict__ out1, uint32* __restrict__ cnt, float* __restrict__ out2)
{
    int gid = blockIdx.x * blockDim.x + threadIdx.x;
    if (gid >= NPOINTS) return;
    int b = gid / NPTS;
    int n = gid - b * NPTS;
    const float* cb = coords + (size_t)b * 3 * NPTS + n;
    float fx = fminf(fmaxf(cb[0]        * 32.0f, 0.0f), 31.0f);
    float fy = fminf(fmaxf(cb[NPTS]     * 32.0f, 0.0f), 31.0f);
    float fz = fminf(fmaxf(cb[2 * NPTS] * 32.0f, 0.0f), 31.0f);
    int x = (int)rintf(fx), y = (int)rintf(fy), z = (int)rintf(fz);
    int v = x * (RR * RR) + y * RR + z;
    float* o2 = out2 + (size_t)b * 3 * NPTS + n;
    o2[0] = (float)x; o2[NPTS] = (float)y; o2[2 * NPTS] = (float)z;
    atomicAdd(&cnt[b * R3 + v], 1u);
    float* obase = out1 + (size_t)(b * CH) * R3 + v;
    const float* frow = feat + (size_t)(b * CH) * NPTS + n;
#pragma unroll 8
    for (int c = 0; c < CH; ++c)
        unsafeAtomicAdd(&obase[(size_t)c * R3], frow[(size_t)c * NPTS]);
}

__global__ __launch_bounds__(256) void finalize_direct(
    float* __restrict__ out1, const uint32* __restrict__ cnt)
{
    size_t gid = (size_t)blockIdx.x * blockDim.x + threadIdx.x;
    size_t total = (size_t)BATCH * CH * R3;
    if (gid >= total) return;
    int v = (int)(gid & (R3 - 1));
    int b = (int)(gid / ((size_t)CH * R3));
    uint32 ct = cnt[b * R3 + v];
    out1[gid] = out1[gid] / (float)(ct > 1u ? ct : 1u);
}

// ---------------------------------------------------------------------------
extern "C" void kernel_launch(void* const* d_in, const int* in_sizes, int n_in,
                              void* d_out, int out_size, void* d_ws, size_t ws_size,
                              hipStream_t stream)
{
    const float* feat   = (const float*)d_in[0];   // [8, 64, 100000]
    const float* coords = (const float*)d_in[1];   // [8, 3, 100000]

    float* out1 = (float*)d_out;                          // [8, 64, 32768]
    float* out2 = out1 + (size_t)BATCH * CH * R3;         // [8, 3, 100000]

    const size_t vox_off    = 0;
    const size_t vox_bytes  = (size_t)NPOINTS * 4;
    const size_t cnt_off    = vox_off + ((vox_bytes + 255) & ~255ull);
    const size_t cnt_bytes  = (size_t)NVOX * 4;
    const size_t starts_off = cnt_off + ((cnt_bytes + 255) & ~255ull);
    const size_t cursor_off = starts_off + ((cnt_bytes + 255) & ~255ull);
    const size_t bsum_off   = cursor_off + ((cnt_bytes + 255) & ~255ull);
    const size_t bsum_bytes = (size_t)SCAN_BLOCKS * 4;
    const size_t sort_off   = (bsum_off + bsum_bytes + 255) & ~255ull;
    const size_t sort_bytes = (size_t)NPOINTS * 128;
    const size_t need       = sort_off + sort_bytes;

    const int pair_blocks = (NPOINTS / 2 + 255) / 256;   // 1563

    if (ws_size >= need) {
        char* ws = (char*)d_ws;
        uint32* vox    = (uint32*)(ws + vox_off);
        uint32* cnt    = (uint32*)(ws + cnt_off);
        uint32* starts = (uint32*)(ws + starts_off);
        uint32* cursor = (uint32*)(ws + cursor_off);
        uint32* bsum   = (uint32*)(ws + bsum_off);
        uint32* sorted = (uint32*)(ws + sort_off);

        (void)hipMemsetAsync(cnt, 0, cnt_bytes, stream);
        phase1_count<<<pair_blocks, 256, 0, stream>>>(coords, vox, cnt, out2);
        scan_block_sums<<<SCAN_BLOCKS, 256, 0, stream>>>(cnt, bsum);
        scan_bsum<<<1, 256, 0, stream>>>(bsum);
        scan_final<<<SCAN_BLOCKS, 256, 0, stream>>>(cnt, bsum, starts, cursor);
        phase3_scatter<<<pair_blocks, 256, 0, stream>>>(feat, vox, cursor, (uintx4*)sorted);
        phase4_reduce<<<NVOX / 64, 256, 0, stream>>>(sorted, starts, out1);
    } else {
        uint32* cnt = (uint32*)d_ws;
        (void)hipMemsetAsync(out1, 0, (size_t)BATCH * CH * R3 * sizeof(float), stream);
        (void)hipMemsetAsync(d_ws, 0, (size_t)NVOX * 4, stream);
        accum_direct<<<(NPOINTS + 255) / 256, 256, 0, stream>>>(feat, coords, out1, cnt, out2);
        size_t total = (size_t)BATCH * CH * R3;
        finalize_direct<<<(unsigned)((total + 255) / 256), 256, 0, stream>>>(out1, cnt);
    }
}